// Round 12
// baseline (466.742 us; speedup 1.0000x reference)
//
#include <hip/hip_runtime.h>

// LayerGCN: out = relu(bn2(relu(bn1( (D^-.5 (A>=.1) D^-.5) V @ W1 )) @ W2))
// B=4096, N=128, C_IN=64, C_HID=256, C_OUT=128.
// R12: gcn_prop unchanged (R5). gcn_mlp v7: wave = 32 rows x FULL width (hP read
// once), only W1 in LDS (33.5KB -> 3+ blocks/CU, 12 waves), W2 streamed from L2
// in tile-contiguous coalesced layout (1KB/load, L2-resident), arch live ~80.

#define THRESH 0.1f
#define BN_EPS 1e-5f

typedef __attribute__((ext_vector_type(8))) short bf16x8;
typedef __attribute__((ext_vector_type(4))) float f32x4;

__device__ __forceinline__ unsigned short f2bf(float f) {
    union { float f; unsigned u; } x; x.f = f;
    unsigned r = x.u + 0x7FFFu + ((x.u >> 16) & 1u);   // RNE
    return (unsigned short)(r >> 16);
}

__device__ __forceinline__ unsigned cvt_pk(float lo, float hi) {
    unsigned r;
    asm("v_cvt_pk_bf16_f32 %0, %1, %2" : "=v"(r) : "v"(lo), "v"(hi));
    return r;
}

// ---------------- prep ----------------
// Shared k-bijection within each 32-chunk (k summed -> legal): register slot j of
// lane-group g holds logical k = 32T + 16(j>>2) + 4g + (j&3).
// W1s: [256][64] u16 with LDS bank-swizzle baked in (16B-slot s at sp = s^(n&7)).
// W2q: tile-contiguous for coalesced L2 streaming:
//   W2q[(T*8+ct3)*512 + (g*16+r16)*8 + j] = bf16(W2[k][n]*sc2[n]),
//   n = ct3*16+r16, k = 32T+16(j>>2)+4g+(j&3). One bw load = contiguous 1KB/wave.
__global__ void gcn_prep(const float* __restrict__ W1, const float* __restrict__ b1,
                         const float* __restrict__ g1, const float* __restrict__ be1,
                         const float* __restrict__ rm1, const float* __restrict__ rv1,
                         const float* __restrict__ W2, const float* __restrict__ b2,
                         const float* __restrict__ g2, const float* __restrict__ be2,
                         const float* __restrict__ rm2, const float* __restrict__ rv2,
                         unsigned short* __restrict__ W1s, unsigned short* __restrict__ W2q,
                         float* __restrict__ sh1, float* __restrict__ sh2) {
    int t = blockIdx.x * blockDim.x + threadIdx.x;       // 0..32767
    if (t < 256 * 64) {                                  // W1s: n = t/64, kp = t%64
        int n = t >> 6, kp = t & 63;
        int sp = kp >> 3, lo = kp & 7;
        int s  = sp ^ (n & 7);
        int k2 = s * 8 + lo;
        int r = k2 & 3, aa = (k2 >> 2) & 1, gg = (k2 >> 3) & 3, T = k2 >> 5;
        int k = T * 32 + aa * 16 + gg * 4 + r;
        float sc = g1[n] * rsqrtf(rv1[n] + BN_EPS);
        W1s[t] = f2bf(W1[k * 256 + n] * sc);
    }
    {                                                    // W2q: tile-contiguous
        int j  = t & 7;
        int rr = (t >> 3) & 15;
        int gg = (t >> 7) & 3;
        int c3 = (t >> 9) & 7;
        int T  = t >> 12;
        int n  = c3 * 16 + rr;
        int k  = T * 32 + 16 * (j >> 2) + 4 * gg + (j & 3);
        float sc = g2[n] * rsqrtf(rv2[n] + BN_EPS);
        W2q[t] = f2bf(W2[k * 128 + n] * sc);
    }
    if (t < 256) {
        float s = g1[t] * rsqrtf(rv1[t] + BN_EPS);
        sh1[t] = (b1[t] - rm1[t]) * s + be1[t];
    }
    if (t < 128) {
        float s = g2[t] * rsqrtf(rv2[t] + BN_EPS);
        sh2[t] = (b2[t] - rm2[t]) * s + be2[t];
    }
}

// ---------------- kernel 1: propagate  A,V -> hP  (unchanged from R5) ----------------
__global__ void __launch_bounds__(256, 5)
gcn_prop(const float* __restrict__ A, const float* __restrict__ V,
         unsigned short* __restrict__ hP) {
    __shared__ unsigned short s_vtt[64 * 136];   // vtt[c][m] = bf16(v[m][c]*dinv[m])

    const int t    = threadIdx.x;
    const int lane = t & 63;
    const int w    = t >> 6;
    const int r16  = lane & 15;
    const int g    = lane >> 4;
    const int b    = blockIdx.x;

    const int mloc  = lane & 31;
    const int chalf = (lane >> 5) * 32;
    const float* vb = V + (size_t)b * 8192 + (size_t)(32 * w + mloc) * 64 + chalf;
    f32x4 pv[8];
#pragma unroll
    for (int q = 0; q < 8; ++q) pv[q] = *(const f32x4*)(vb + 4 * q);

    const float* ab = A + (size_t)b * 16384 + (size_t)(32 * w + r16) * 128;
    bf16x8 afrag[2][4];
    int cnt0 = 0, cnt1 = 0;
#pragma unroll
    for (int mt = 0; mt < 2; ++mt)
#pragma unroll
        for (int ks = 0; ks < 4; ++ks) {
            const float* p = ab + mt * 2048 + ks * 32 + 8 * g;
            f32x4 x0 = *(const f32x4*)p;
            f32x4 x1 = *(const f32x4*)(p + 4);
            union { unsigned short s[8]; bf16x8 v; } u;
            u.s[0] = (x0.x >= THRESH) ? (unsigned short)0x3F80u : (unsigned short)0u;
            u.s[1] = (x0.y >= THRESH) ? (unsigned short)0x3F80u : (unsigned short)0u;
            u.s[2] = (x0.z >= THRESH) ? (unsigned short)0x3F80u : (unsigned short)0u;
            u.s[3] = (x0.w >= THRESH) ? (unsigned short)0x3F80u : (unsigned short)0u;
            u.s[4] = (x1.x >= THRESH) ? (unsigned short)0x3F80u : (unsigned short)0u;
            u.s[5] = (x1.y >= THRESH) ? (unsigned short)0x3F80u : (unsigned short)0u;
            u.s[6] = (x1.z >= THRESH) ? (unsigned short)0x3F80u : (unsigned short)0u;
            u.s[7] = (x1.w >= THRESH) ? (unsigned short)0x3F80u : (unsigned short)0u;
            afrag[mt][ks] = u.v;
            int c = (x0.x >= THRESH) + (x0.y >= THRESH) + (x0.z >= THRESH) + (x0.w >= THRESH)
                  + (x1.x >= THRESH) + (x1.y >= THRESH) + (x1.z >= THRESH) + (x1.w >= THRESH);
            if (mt == 0) cnt0 += c; else cnt1 += c;
        }
    cnt0 += __shfl_xor(cnt0, 16); cnt0 += __shfl_xor(cnt0, 32);
    cnt1 += __shfl_xor(cnt1, 16); cnt1 += __shfl_xor(cnt1, 32);
    const float dinv0 = rsqrtf((float)cnt0);
    const float dinv1 = rsqrtf((float)cnt1);

    {
        float dm = (lane & 16) ? dinv1 : dinv0;
        int m = 32 * w + mloc;
#pragma unroll
        for (int q = 0; q < 8; ++q) {
            int c = chalf + 4 * q;
            s_vtt[(c + 0) * 136 + m] = f2bf(pv[q].x * dm);
            s_vtt[(c + 1) * 136 + m] = f2bf(pv[q].y * dm);
            s_vtt[(c + 2) * 136 + m] = f2bf(pv[q].z * dm);
            s_vtt[(c + 3) * 136 + m] = f2bf(pv[q].w * dm);
        }
    }
    __syncthreads();

    f32x4 acc1[4][2];
#pragma unroll
    for (int ct = 0; ct < 4; ++ct)
#pragma unroll
        for (int mt = 0; mt < 2; ++mt) acc1[ct][mt] = f32x4{0.f, 0.f, 0.f, 0.f};
#pragma unroll
    for (int ks = 0; ks < 4; ++ks)
#pragma unroll
        for (int ct = 0; ct < 4; ++ct) {
            bf16x8 av = *(const bf16x8*)(s_vtt + (ct * 16 + r16) * 136 + ks * 32 + 8 * g);
            acc1[ct][0] = __builtin_amdgcn_mfma_f32_16x16x32_bf16(av, afrag[0][ks], acc1[ct][0], 0, 0, 0);
            acc1[ct][1] = __builtin_amdgcn_mfma_f32_16x16x32_bf16(av, afrag[1][ks], acc1[ct][1], 0, 0, 0);
        }

#pragma unroll
    for (int mt = 0; mt < 2; ++mt) {
        float d = (mt == 0) ? dinv0 : dinv1;
        size_t m = (size_t)(b * 128 + 32 * w + 16 * mt + r16);
#pragma unroll
        for (int ks2 = 0; ks2 < 2; ++ks2) {
            union { unsigned u[4]; bf16x8 v; } pk;
            pk.u[0] = cvt_pk(acc1[2 * ks2][mt][0] * d,     acc1[2 * ks2][mt][1] * d);
            pk.u[1] = cvt_pk(acc1[2 * ks2][mt][2] * d,     acc1[2 * ks2][mt][3] * d);
            pk.u[2] = cvt_pk(acc1[2 * ks2 + 1][mt][0] * d, acc1[2 * ks2 + 1][mt][1] * d);
            pk.u[3] = cvt_pk(acc1[2 * ks2 + 1][mt][2] * d, acc1[2 * ks2 + 1][mt][3] * d);
            *(bf16x8*)(hP + m * 64 + ks2 * 32 + 8 * g) = pk.v;
        }
    }
}

// ---------------- kernel 2: MLP  hP -> out  (v7: W1-LDS, W2-L2-stream) ----------------
// 256 thr = 4 waves; wave w owns rows (chunk + 32w .. +31), FULL 128 out-cols.
// Block: 8 chunks of 128 rows (1024 rows). Grid 512. hP read ONCE per row.
// LDS 34304 B only -> 3+ blocks/CU (12 waves). Per T: 4 LDS aw + 8 L2 bw -> 24 MFMA.
__global__ void __launch_bounds__(256, 3)
gcn_mlp(const unsigned short* __restrict__ hP,
        const unsigned short* __restrict__ W1s, const unsigned short* __restrict__ W2q,
        const float* __restrict__ sh1g, const float* __restrict__ sh2g,
        float* __restrict__ out) {
    __shared__ char smem[34304];
    unsigned short* W1L = (unsigned short*)smem;            // [256][64] u16, swizzled (32KB)
    float* s_sh1 = (float*)(smem + 32768);                  // [256]
    float* s_sh2 = (float*)(smem + 33792);                  // [128]

    const int t    = threadIdx.x;
    const int lane = t & 63;
    const int w    = t >> 6;
    const int r16  = lane & 15;
    const int g    = lane >> 4;

    // stage W1 (32 KB linear; swizzle baked in by prep)
#pragma unroll
    for (int q = 0; q < 8; ++q)
        *(f32x4*)(smem + t * 128 + q * 16) = *(const f32x4*)((const char*)W1s + t * 128 + q * 16);
    s_sh1[t] = sh1g[t];
    if (t < 128) s_sh2[t] = sh2g[t];
    __syncthreads();   // only barrier in the kernel

    const size_t row0 = (size_t)blockIdx.x * 1024;   // 8 chunks x 128 rows

#pragma unroll 1
    for (int i = 0; i < 8; ++i) {
        const size_t mb = row0 + i * 128 + 32 * w;   // wave's 32 rows

        bf16x8 bh[2][2];
#pragma unroll
        for (int mt = 0; mt < 2; ++mt)
#pragma unroll
            for (int ks2 = 0; ks2 < 2; ++ks2)
                bh[mt][ks2] = *(const bf16x8*)(hP + (mb + 16 * mt + r16) * 64 + ks2 * 32 + 8 * g);

        f32x4 acc3[2][8];
#pragma unroll
        for (int mt = 0; mt < 2; ++mt)
#pragma unroll
            for (int ct = 0; ct < 8; ++ct) acc3[mt][ct] = f32x4{0.f, 0.f, 0.f, 0.f};

#pragma unroll
        for (int T = 0; T < 8; ++T) {
            // GEMM2: a2[mt][ctp][r] = x1_pre[m=mb+16mt+r16][c=(2T+ctp)*16+4g+r]
            f32x4 a2[2][2];
#pragma unroll
            for (int mt = 0; mt < 2; ++mt)
#pragma unroll
                for (int ctp = 0; ctp < 2; ++ctp) a2[mt][ctp] = f32x4{0.f, 0.f, 0.f, 0.f};
#pragma unroll
            for (int ctp = 0; ctp < 2; ++ctp) {
                int n = (2 * T + ctp) * 16 + r16;
#pragma unroll
                for (int ks2 = 0; ks2 < 2; ++ks2) {
                    int sp = (ks2 * 4 + g) ^ (n & 7);
                    bf16x8 aw = *(const bf16x8*)(W1L + n * 64 + sp * 8);
                    a2[0][ctp] = __builtin_amdgcn_mfma_f32_16x16x32_bf16(aw, bh[0][ks2], a2[0][ctp], 0, 0, 0);
                    a2[1][ctp] = __builtin_amdgcn_mfma_f32_16x16x32_bf16(aw, bh[1][ks2], a2[1][ctp], 0, 0, 0);
                }
            }
            // BN1 shift + ReLU + bijection pack -> GEMM3 A-frags
            union { unsigned u[4]; bf16x8 v; } af[2];
#pragma unroll
            for (int ctp = 0; ctp < 2; ++ctp) {
                f32x4 sh = *(const f32x4*)(s_sh1 + (2 * T + ctp) * 16 + 4 * g);
#pragma unroll
                for (int mt = 0; mt < 2; ++mt) {
                    float y0 = fmaxf(a2[mt][ctp][0] + sh.x, 0.f);
                    float y1 = fmaxf(a2[mt][ctp][1] + sh.y, 0.f);
                    float y2 = fmaxf(a2[mt][ctp][2] + sh.z, 0.f);
                    float y3 = fmaxf(a2[mt][ctp][3] + sh.w, 0.f);
                    af[mt].u[2 * ctp + 0] = cvt_pk(y0, y1);
                    af[mt].u[2 * ctp + 1] = cvt_pk(y2, y3);
                }
            }
            // GEMM3 partial over k' = 32T..32T+31: bw streamed from L2, 1KB coalesced
#pragma unroll
            for (int ct3 = 0; ct3 < 8; ++ct3) {
                bf16x8 bw = *(const bf16x8*)(W2q + (size_t)(T * 8 + ct3) * 512 + lane * 8);
                acc3[0][ct3] = __builtin_amdgcn_mfma_f32_16x16x32_bf16(af[0].v, bw, acc3[0][ct3], 0, 0, 0);
                acc3[1][ct3] = __builtin_amdgcn_mfma_f32_16x16x32_bf16(af[1].v, bw, acc3[1][ct3], 0, 0, 0);
            }
        }

        // BN2 shift + ReLU -> global
        float* ob = out + mb * 128;
#pragma unroll
        for (int ct3 = 0; ct3 < 8; ++ct3) {
            int c = ct3 * 16 + r16;
            float sh = s_sh2[c];
#pragma unroll
            for (int mt = 0; mt < 2; ++mt)
#pragma unroll
                for (int r = 0; r < 4; ++r) {
                    int row = 16 * mt + 4 * g + r;
                    ob[row * 128 + c] = fmaxf(acc3[mt][ct3][r] + sh, 0.f);
                }
        }
    }
}

extern "C" void kernel_launch(void* const* d_in, const int* in_sizes, int n_in,
                              void* d_out, int out_size, void* d_ws, size_t ws_size,
                              hipStream_t stream) {
    (void)in_sizes; (void)n_in; (void)out_size; (void)ws_size;
    const float* a   = (const float*)d_in[0];
    const float* v   = (const float*)d_in[1];
    const float* W1  = (const float*)d_in[2];
    const float* b1  = (const float*)d_in[3];
    const float* g1  = (const float*)d_in[4];
    const float* be1 = (const float*)d_in[5];
    const float* rm1 = (const float*)d_in[6];
    const float* rv1 = (const float*)d_in[7];
    const float* W2  = (const float*)d_in[8];
    const float* b2  = (const float*)d_in[9];
    const float* g2  = (const float*)d_in[10];
    const float* be2 = (const float*)d_in[11];
    const float* rm2 = (const float*)d_in[12];
    const float* rv2 = (const float*)d_in[13];

    char* ws = (char*)d_ws;
    unsigned short* W1s = (unsigned short*)ws;             // 32768 B
    unsigned short* W2q = (unsigned short*)(ws + 32768);   // 65536 B
    float* sh1 = (float*)(ws + 98304);                     // 1024 B
    float* sh2 = (float*)(ws + 99328);                     // 512 B
    unsigned short* hP = (unsigned short*)(ws + 102400);   // 67108864 B (64 MB)

    gcn_prep<<<128, 256, 0, stream>>>(W1, b1, g1, be1, rm1, rv1,
                                      W2, b2, g2, be2, rm2, rv2,
                                      W1s, W2q, sh1, sh2);
    gcn_prop<<<4096, 256, 0, stream>>>(a, v, hP);
    gcn_mlp<<<512, 256, 0, stream>>>(hP, W1s, W2q, sh1, sh2, (float*)d_out);
}

// Round 13
// 269.258 us; speedup vs baseline: 1.7334x; 1.7334x over previous
//
#include <hip/hip_runtime.h>

// LayerGCN: out = relu(bn2(relu(bn1( (D^-.5 (A>=.1) D^-.5) V @ W1 )) @ W2))
// B=4096, N=128, C_IN=64, C_HID=256, C_OUT=128.
// R13: gcn_prop unchanged (R5). gcn_mlp v8: 1024-thr block (16 waves, 4/SIMD),
// FULL W1+W2 in LDS (97.5KB, 1 block/CU), wave = 32 rows x 64 out-cols
// (col-split INSIDE block -> hP read once/CU), acc3[2][4], arch live ~112 < 128.

#define THRESH 0.1f
#define BN_EPS 1e-5f

typedef __attribute__((ext_vector_type(8))) short bf16x8;
typedef __attribute__((ext_vector_type(4))) float f32x4;

__device__ __forceinline__ unsigned short f2bf(float f) {
    union { float f; unsigned u; } x; x.f = f;
    unsigned r = x.u + 0x7FFFu + ((x.u >> 16) & 1u);   // RNE
    return (unsigned short)(r >> 16);
}

__device__ __forceinline__ unsigned cvt_pk(float lo, float hi) {
    unsigned r;
    asm("v_cvt_pk_bf16_f32 %0, %1, %2" : "=v"(r) : "v"(lo), "v"(hi));
    return r;
}

// ---------------- prep ----------------
// k-bijection within each 32-chunk (k summed -> legal): register slot j of
// lane-group g holds logical k = 32T + 16(j>>2) + 4g + (j&3).
// LDS bank-swizzle baked in: 16B-slot s stored at sp = s ^ (n&7).
// W1s: [256][64] u16. W2s: [128][256] u16.
__global__ void gcn_prep(const float* __restrict__ W1, const float* __restrict__ b1,
                         const float* __restrict__ g1, const float* __restrict__ be1,
                         const float* __restrict__ rm1, const float* __restrict__ rv1,
                         const float* __restrict__ W2, const float* __restrict__ b2,
                         const float* __restrict__ g2, const float* __restrict__ be2,
                         const float* __restrict__ rm2, const float* __restrict__ rv2,
                         unsigned short* __restrict__ W1s, unsigned short* __restrict__ W2s,
                         float* __restrict__ sh1, float* __restrict__ sh2) {
    int t = blockIdx.x * blockDim.x + threadIdx.x;       // 0..32767
    if (t < 256 * 64) {                                  // W1s: n = t/64, kp = t%64
        int n = t >> 6, kp = t & 63;
        int sp = kp >> 3, lo = kp & 7;
        int s  = sp ^ (n & 7);
        int k2 = s * 8 + lo;
        int r = k2 & 3, aa = (k2 >> 2) & 1, gg = (k2 >> 3) & 3, T = k2 >> 5;
        int k = T * 32 + aa * 16 + gg * 4 + r;
        float sc = g1[n] * rsqrtf(rv1[n] + BN_EPS);
        W1s[t] = f2bf(W1[k * 256 + n] * sc);
    }
    {                                                    // W2s: n = t/256, kp = t%256
        int n = t >> 8, kp = t & 255;
        int sp = kp >> 3, lo = kp & 7;
        int s  = sp ^ (n & 7);
        int k2 = s * 8 + lo;
        int r = k2 & 3, aa = (k2 >> 2) & 1, gg = (k2 >> 3) & 3, T = k2 >> 5;
        int k = T * 32 + aa * 16 + gg * 4 + r;
        float sc = g2[n] * rsqrtf(rv2[n] + BN_EPS);
        W2s[t] = f2bf(W2[k * 128 + n] * sc);
    }
    if (t < 256) {
        float s = g1[t] * rsqrtf(rv1[t] + BN_EPS);
        sh1[t] = (b1[t] - rm1[t]) * s + be1[t];
    }
    if (t < 128) {
        float s = g2[t] * rsqrtf(rv2[t] + BN_EPS);
        sh2[t] = (b2[t] - rm2[t]) * s + be2[t];
    }
}

// ---------------- kernel 1: propagate  A,V -> hP  (unchanged from R5) ----------------
__global__ void __launch_bounds__(256, 5)
gcn_prop(const float* __restrict__ A, const float* __restrict__ V,
         unsigned short* __restrict__ hP) {
    __shared__ unsigned short s_vtt[64 * 136];   // vtt[c][m] = bf16(v[m][c]*dinv[m])

    const int t    = threadIdx.x;
    const int lane = t & 63;
    const int w    = t >> 6;
    const int r16  = lane & 15;
    const int g    = lane >> 4;
    const int b    = blockIdx.x;

    const int mloc  = lane & 31;
    const int chalf = (lane >> 5) * 32;
    const float* vb = V + (size_t)b * 8192 + (size_t)(32 * w + mloc) * 64 + chalf;
    f32x4 pv[8];
#pragma unroll
    for (int q = 0; q < 8; ++q) pv[q] = *(const f32x4*)(vb + 4 * q);

    const float* ab = A + (size_t)b * 16384 + (size_t)(32 * w + r16) * 128;
    bf16x8 afrag[2][4];
    int cnt0 = 0, cnt1 = 0;
#pragma unroll
    for (int mt = 0; mt < 2; ++mt)
#pragma unroll
        for (int ks = 0; ks < 4; ++ks) {
            const float* p = ab + mt * 2048 + ks * 32 + 8 * g;
            f32x4 x0 = *(const f32x4*)p;
            f32x4 x1 = *(const f32x4*)(p + 4);
            union { unsigned short s[8]; bf16x8 v; } u;
            u.s[0] = (x0.x >= THRESH) ? (unsigned short)0x3F80u : (unsigned short)0u;
            u.s[1] = (x0.y >= THRESH) ? (unsigned short)0x3F80u : (unsigned short)0u;
            u.s[2] = (x0.z >= THRESH) ? (unsigned short)0x3F80u : (unsigned short)0u;
            u.s[3] = (x0.w >= THRESH) ? (unsigned short)0x3F80u : (unsigned short)0u;
            u.s[4] = (x1.x >= THRESH) ? (unsigned short)0x3F80u : (unsigned short)0u;
            u.s[5] = (x1.y >= THRESH) ? (unsigned short)0x3F80u : (unsigned short)0u;
            u.s[6] = (x1.z >= THRESH) ? (unsigned short)0x3F80u : (unsigned short)0u;
            u.s[7] = (x1.w >= THRESH) ? (unsigned short)0x3F80u : (unsigned short)0u;
            afrag[mt][ks] = u.v;
            int c = (x0.x >= THRESH) + (x0.y >= THRESH) + (x0.z >= THRESH) + (x0.w >= THRESH)
                  + (x1.x >= THRESH) + (x1.y >= THRESH) + (x1.z >= THRESH) + (x1.w >= THRESH);
            if (mt == 0) cnt0 += c; else cnt1 += c;
        }
    cnt0 += __shfl_xor(cnt0, 16); cnt0 += __shfl_xor(cnt0, 32);
    cnt1 += __shfl_xor(cnt1, 16); cnt1 += __shfl_xor(cnt1, 32);
    const float dinv0 = rsqrtf((float)cnt0);
    const float dinv1 = rsqrtf((float)cnt1);

    {
        float dm = (lane & 16) ? dinv1 : dinv0;
        int m = 32 * w + mloc;
#pragma unroll
        for (int q = 0; q < 8; ++q) {
            int c = chalf + 4 * q;
            s_vtt[(c + 0) * 136 + m] = f2bf(pv[q].x * dm);
            s_vtt[(c + 1) * 136 + m] = f2bf(pv[q].y * dm);
            s_vtt[(c + 2) * 136 + m] = f2bf(pv[q].z * dm);
            s_vtt[(c + 3) * 136 + m] = f2bf(pv[q].w * dm);
        }
    }
    __syncthreads();

    f32x4 acc1[4][2];
#pragma unroll
    for (int ct = 0; ct < 4; ++ct)
#pragma unroll
        for (int mt = 0; mt < 2; ++mt) acc1[ct][mt] = f32x4{0.f, 0.f, 0.f, 0.f};
#pragma unroll
    for (int ks = 0; ks < 4; ++ks)
#pragma unroll
        for (int ct = 0; ct < 4; ++ct) {
            bf16x8 av = *(const bf16x8*)(s_vtt + (ct * 16 + r16) * 136 + ks * 32 + 8 * g);
            acc1[ct][0] = __builtin_amdgcn_mfma_f32_16x16x32_bf16(av, afrag[0][ks], acc1[ct][0], 0, 0, 0);
            acc1[ct][1] = __builtin_amdgcn_mfma_f32_16x16x32_bf16(av, afrag[1][ks], acc1[ct][1], 0, 0, 0);
        }

#pragma unroll
    for (int mt = 0; mt < 2; ++mt) {
        float d = (mt == 0) ? dinv0 : dinv1;
        size_t m = (size_t)(b * 128 + 32 * w + 16 * mt + r16);
#pragma unroll
        for (int ks2 = 0; ks2 < 2; ++ks2) {
            union { unsigned u[4]; bf16x8 v; } pk;
            pk.u[0] = cvt_pk(acc1[2 * ks2][mt][0] * d,     acc1[2 * ks2][mt][1] * d);
            pk.u[1] = cvt_pk(acc1[2 * ks2][mt][2] * d,     acc1[2 * ks2][mt][3] * d);
            pk.u[2] = cvt_pk(acc1[2 * ks2 + 1][mt][0] * d, acc1[2 * ks2 + 1][mt][1] * d);
            pk.u[3] = cvt_pk(acc1[2 * ks2 + 1][mt][2] * d, acc1[2 * ks2 + 1][mt][3] * d);
            *(bf16x8*)(hP + m * 64 + ks2 * 32 + 8 * g) = pk.v;
        }
    }
}

// ---------------- kernel 2: MLP  hP -> out  (v8: 16 waves, full LDS weights) ----------------
// 1024 thr = 16 waves (4/SIMD); wave w: rslot=w>>1 (32 rows), ch=w&1 (64 out-cols).
// Chunk = 256 rows; 8 chunks per block (2048 rows); grid 256 = 1 block/CU.
// hP read once per CU (col-halves share rows inside the block). GEMM2 dup x2.
// LDS: W1L 32K | W2L 64K | sh 1.5K. Per T: 4 aw + 4 bw ds_reads -> 16 MFMA.
__global__ void __launch_bounds__(1024, 1)
gcn_mlp(const unsigned short* __restrict__ hP,
        const unsigned short* __restrict__ W1s, const unsigned short* __restrict__ W2s,
        const float* __restrict__ sh1g, const float* __restrict__ sh2g,
        float* __restrict__ out) {
    __shared__ char smem[99840];
    unsigned short* W1L = (unsigned short*)smem;            // [256][64] u16, swizzled
    unsigned short* W2L = (unsigned short*)(smem + 32768);  // [128][256] u16, swizzled
    float* s_sh1 = (float*)(smem + 98304);
    float* s_sh2 = (float*)(smem + 99328);

    const int t     = threadIdx.x;       // 0..1023
    const int lane  = t & 63;
    const int w     = t >> 6;            // 0..15
    const int r16   = lane & 15;
    const int g     = lane >> 4;
    const int rslot = w >> 1;            // 0..7: row group within chunk
    const int ch    = w & 1;             // out-col half

    // ---- stage weights (linear copies; swizzle baked in by prep) ----
#pragma unroll
    for (int q = 0; q < 2; ++q)
        *(f32x4*)(smem + t * 32 + q * 16) = *(const f32x4*)((const char*)W1s + t * 32 + q * 16);
#pragma unroll
    for (int q = 0; q < 4; ++q)
        *(f32x4*)(smem + 32768 + t * 64 + q * 16) =
            *(const f32x4*)((const char*)W2s + t * 64 + q * 16);
    if (t < 256) s_sh1[t] = sh1g[t];
    if (t < 128) s_sh2[t] = sh2g[t];
    __syncthreads();   // only barrier in the kernel

    const size_t row0 = (size_t)blockIdx.x * 2048;   // 8 chunks x 256 rows

#pragma unroll 1
    for (int i = 0; i < 8; ++i) {
        const size_t mb = row0 + i * 256 + rslot * 32;   // wave's 32 rows

        bf16x8 bh[2][2];
#pragma unroll
        for (int mt = 0; mt < 2; ++mt)
#pragma unroll
            for (int ks2 = 0; ks2 < 2; ++ks2)
                bh[mt][ks2] = *(const bf16x8*)(hP + (mb + 16 * mt + r16) * 64 + ks2 * 32 + 8 * g);

        f32x4 acc3[2][4];
#pragma unroll
        for (int mt = 0; mt < 2; ++mt)
#pragma unroll
            for (int q = 0; q < 4; ++q) acc3[mt][q] = f32x4{0.f, 0.f, 0.f, 0.f};

#pragma unroll
        for (int T = 0; T < 8; ++T) {
            // GEMM2 (full width, dup x2 across col-half waves):
            // a2[mt][ctp][r] = x1_pre[m=mb+16mt+r16][c=(2T+ctp)*16+4g+r]
            f32x4 a2[2][2];
#pragma unroll
            for (int mt = 0; mt < 2; ++mt)
#pragma unroll
                for (int ctp = 0; ctp < 2; ++ctp) a2[mt][ctp] = f32x4{0.f, 0.f, 0.f, 0.f};
#pragma unroll
            for (int ctp = 0; ctp < 2; ++ctp) {
                int n = (2 * T + ctp) * 16 + r16;
#pragma unroll
                for (int ks2 = 0; ks2 < 2; ++ks2) {
                    int sp = (ks2 * 4 + g) ^ (n & 7);
                    bf16x8 aw = *(const bf16x8*)(W1L + n * 64 + sp * 8);
                    a2[0][ctp] = __builtin_amdgcn_mfma_f32_16x16x32_bf16(aw, bh[0][ks2], a2[0][ctp], 0, 0, 0);
                    a2[1][ctp] = __builtin_amdgcn_mfma_f32_16x16x32_bf16(aw, bh[1][ks2], a2[1][ctp], 0, 0, 0);
                }
            }
            // BN1 shift + ReLU + bijection pack -> GEMM3 A-frags
            union { unsigned u[4]; bf16x8 v; } af[2];
#pragma unroll
            for (int ctp = 0; ctp < 2; ++ctp) {
                f32x4 sh = *(const f32x4*)(s_sh1 + (2 * T + ctp) * 16 + 4 * g);
#pragma unroll
                for (int mt = 0; mt < 2; ++mt) {
                    float y0 = fmaxf(a2[mt][ctp][0] + sh.x, 0.f);
                    float y1 = fmaxf(a2[mt][ctp][1] + sh.y, 0.f);
                    float y2 = fmaxf(a2[mt][ctp][2] + sh.z, 0.f);
                    float y3 = fmaxf(a2[mt][ctp][3] + sh.w, 0.f);
                    af[mt].u[2 * ctp + 0] = cvt_pk(y0, y1);
                    af[mt].u[2 * ctp + 1] = cvt_pk(y2, y3);
                }
            }
            // GEMM3 partial over k' = 32T..32T+31: this wave's 4 col-tiles from LDS
#pragma unroll
            for (int q = 0; q < 4; ++q) {
                int nl = ch * 64 + q * 16 + r16;            // W2 row (out col)
                int sp = (T * 4 + g) ^ (nl & 7);
                bf16x8 bw = *(const bf16x8*)(W2L + nl * 256 + sp * 8);
                acc3[0][q] = __builtin_amdgcn_mfma_f32_16x16x32_bf16(af[0].v, bw, acc3[0][q], 0, 0, 0);
                acc3[1][q] = __builtin_amdgcn_mfma_f32_16x16x32_bf16(af[1].v, bw, acc3[1][q], 0, 0, 0);
            }
        }

        // BN2 shift + ReLU -> global (cols ch*64 .. +63)
        float* ob = out + mb * 128 + ch * 64;
#pragma unroll
        for (int q = 0; q < 4; ++q) {
            int cl = q * 16 + r16;
            float sh = s_sh2[ch * 64 + cl];
#pragma unroll
            for (int mt = 0; mt < 2; ++mt)
#pragma unroll
                for (int r = 0; r < 4; ++r) {
                    int row = 16 * mt + 4 * g + r;
                    ob[row * 128 + cl] = fmaxf(acc3[mt][q][r] + sh, 0.f);
                }
        }
    }
}

extern "C" void kernel_launch(void* const* d_in, const int* in_sizes, int n_in,
                              void* d_out, int out_size, void* d_ws, size_t ws_size,
                              hipStream_t stream) {
    (void)in_sizes; (void)n_in; (void)out_size; (void)ws_size;
    const float* a   = (const float*)d_in[0];
    const float* v   = (const float*)d_in[1];
    const float* W1  = (const float*)d_in[2];
    const float* b1  = (const float*)d_in[3];
    const float* g1  = (const float*)d_in[4];
    const float* be1 = (const float*)d_in[5];
    const float* rm1 = (const float*)d_in[6];
    const float* rv1 = (const float*)d_in[7];
    const float* W2  = (const float*)d_in[8];
    const float* b2  = (const float*)d_in[9];
    const float* g2  = (const float*)d_in[10];
    const float* be2 = (const float*)d_in[11];
    const float* rm2 = (const float*)d_in[12];
    const float* rv2 = (const float*)d_in[13];

    char* ws = (char*)d_ws;
    unsigned short* W1s = (unsigned short*)ws;             // 32768 B
    unsigned short* W2s = (unsigned short*)(ws + 32768);   // 65536 B
    float* sh1 = (float*)(ws + 98304);                     // 1024 B
    float* sh2 = (float*)(ws + 99328);                     // 512 B
    unsigned short* hP = (unsigned short*)(ws + 102400);   // 67108864 B (64 MB)

    gcn_prep<<<128, 256, 0, stream>>>(W1, b1, g1, be1, rm1, rv1,
                                      W2, b2, g2, be2, rm2, rv2,
                                      W1s, W2s, sh1, sh2);
    gcn_prop<<<4096, 256, 0, stream>>>(a, v, hP);
    gcn_mlp<<<256, 1024, 0, stream>>>(hP, W1s, W2s, sh1, sh2, (float*)d_out);
}

// Round 14
// 202.748 us; speedup vs baseline: 2.3021x; 1.3280x over previous
//
#include <hip/hip_runtime.h>

// LayerGCN: out = relu(bn2(relu(bn1( (D^-.5 (A>=.1) D^-.5) V @ W1 )) @ W2))
// B=4096, N=128, C_IN=64, C_HID=256, C_OUT=128.
// R14: prop -> (256,4) (was (256,5): 102-VGPR clamp < ~110 live = chronic spill).
// mlp = R7's minimal-work structure (wave = 32 rows x FULL width, zero dup MFMA,
// W1+W2 in LDS) minus the cross-chunk prefetch (live 142 -> ~126 <= 128 cap).

#define THRESH 0.1f
#define BN_EPS 1e-5f

typedef __attribute__((ext_vector_type(8))) short bf16x8;
typedef __attribute__((ext_vector_type(4))) float f32x4;

__device__ __forceinline__ unsigned short f2bf(float f) {
    union { float f; unsigned u; } x; x.f = f;
    unsigned r = x.u + 0x7FFFu + ((x.u >> 16) & 1u);   // RNE
    return (unsigned short)(r >> 16);
}

__device__ __forceinline__ unsigned cvt_pk(float lo, float hi) {
    unsigned r;
    asm("v_cvt_pk_bf16_f32 %0, %1, %2" : "=v"(r) : "v"(lo), "v"(hi));
    return r;
}

// ---------------- prep ----------------
// k-bijection within each 32-chunk (k summed -> legal): register slot j of
// lane-group g holds logical k = 32T + 16(j>>2) + 4g + (j&3).
// LDS bank-swizzle baked in: 16B-slot s stored at sp = s ^ (n&7).
// W1s: [256][64] u16. W2s: [128][256] u16.
__global__ void gcn_prep(const float* __restrict__ W1, const float* __restrict__ b1,
                         const float* __restrict__ g1, const float* __restrict__ be1,
                         const float* __restrict__ rm1, const float* __restrict__ rv1,
                         const float* __restrict__ W2, const float* __restrict__ b2,
                         const float* __restrict__ g2, const float* __restrict__ be2,
                         const float* __restrict__ rm2, const float* __restrict__ rv2,
                         unsigned short* __restrict__ W1s, unsigned short* __restrict__ W2s,
                         float* __restrict__ sh1, float* __restrict__ sh2) {
    int t = blockIdx.x * blockDim.x + threadIdx.x;       // 0..32767
    if (t < 256 * 64) {                                  // W1s: n = t/64, kp = t%64
        int n = t >> 6, kp = t & 63;
        int sp = kp >> 3, lo = kp & 7;
        int s  = sp ^ (n & 7);
        int k2 = s * 8 + lo;
        int r = k2 & 3, aa = (k2 >> 2) & 1, gg = (k2 >> 3) & 3, T = k2 >> 5;
        int k = T * 32 + aa * 16 + gg * 4 + r;
        float sc = g1[n] * rsqrtf(rv1[n] + BN_EPS);
        W1s[t] = f2bf(W1[k * 256 + n] * sc);
    }
    {                                                    // W2s: n = t/256, kp = t%256
        int n = t >> 8, kp = t & 255;
        int sp = kp >> 3, lo = kp & 7;
        int s  = sp ^ (n & 7);
        int k2 = s * 8 + lo;
        int r = k2 & 3, aa = (k2 >> 2) & 1, gg = (k2 >> 3) & 3, T = k2 >> 5;
        int k = T * 32 + aa * 16 + gg * 4 + r;
        float sc = g2[n] * rsqrtf(rv2[n] + BN_EPS);
        W2s[t] = f2bf(W2[k * 128 + n] * sc);
    }
    if (t < 256) {
        float s = g1[t] * rsqrtf(rv1[t] + BN_EPS);
        sh1[t] = (b1[t] - rm1[t]) * s + be1[t];
    }
    if (t < 128) {
        float s = g2[t] * rsqrtf(rv2[t] + BN_EPS);
        sh2[t] = (b2[t] - rm2[t]) * s + be2[t];
    }
}

// ---------------- kernel 1: propagate  A,V -> hP  ((256,4): no VGPR clamp-spill) ----------------
__global__ void __launch_bounds__(256, 4)
gcn_prop(const float* __restrict__ A, const float* __restrict__ V,
         unsigned short* __restrict__ hP) {
    __shared__ unsigned short s_vtt[64 * 136];   // vtt[c][m] = bf16(v[m][c]*dinv[m])

    const int t    = threadIdx.x;
    const int lane = t & 63;
    const int w    = t >> 6;
    const int r16  = lane & 15;
    const int g    = lane >> 4;
    const int b    = blockIdx.x;

    const int mloc  = lane & 31;
    const int chalf = (lane >> 5) * 32;
    const float* vb = V + (size_t)b * 8192 + (size_t)(32 * w + mloc) * 64 + chalf;
    f32x4 pv[8];
#pragma unroll
    for (int q = 0; q < 8; ++q) pv[q] = *(const f32x4*)(vb + 4 * q);

    const float* ab = A + (size_t)b * 16384 + (size_t)(32 * w + r16) * 128;
    bf16x8 afrag[2][4];
    int cnt0 = 0, cnt1 = 0;
#pragma unroll
    for (int mt = 0; mt < 2; ++mt)
#pragma unroll
        for (int ks = 0; ks < 4; ++ks) {
            const float* p = ab + mt * 2048 + ks * 32 + 8 * g;
            f32x4 x0 = *(const f32x4*)p;
            f32x4 x1 = *(const f32x4*)(p + 4);
            union { unsigned short s[8]; bf16x8 v; } u;
            u.s[0] = (x0.x >= THRESH) ? (unsigned short)0x3F80u : (unsigned short)0u;
            u.s[1] = (x0.y >= THRESH) ? (unsigned short)0x3F80u : (unsigned short)0u;
            u.s[2] = (x0.z >= THRESH) ? (unsigned short)0x3F80u : (unsigned short)0u;
            u.s[3] = (x0.w >= THRESH) ? (unsigned short)0x3F80u : (unsigned short)0u;
            u.s[4] = (x1.x >= THRESH) ? (unsigned short)0x3F80u : (unsigned short)0u;
            u.s[5] = (x1.y >= THRESH) ? (unsigned short)0x3F80u : (unsigned short)0u;
            u.s[6] = (x1.z >= THRESH) ? (unsigned short)0x3F80u : (unsigned short)0u;
            u.s[7] = (x1.w >= THRESH) ? (unsigned short)0x3F80u : (unsigned short)0u;
            afrag[mt][ks] = u.v;
            int c = (x0.x >= THRESH) + (x0.y >= THRESH) + (x0.z >= THRESH) + (x0.w >= THRESH)
                  + (x1.x >= THRESH) + (x1.y >= THRESH) + (x1.z >= THRESH) + (x1.w >= THRESH);
            if (mt == 0) cnt0 += c; else cnt1 += c;
        }
    cnt0 += __shfl_xor(cnt0, 16); cnt0 += __shfl_xor(cnt0, 32);
    cnt1 += __shfl_xor(cnt1, 16); cnt1 += __shfl_xor(cnt1, 32);
    const float dinv0 = rsqrtf((float)cnt0);
    const float dinv1 = rsqrtf((float)cnt1);

    {
        float dm = (lane & 16) ? dinv1 : dinv0;
        int m = 32 * w + mloc;
#pragma unroll
        for (int q = 0; q < 8; ++q) {
            int c = chalf + 4 * q;
            s_vtt[(c + 0) * 136 + m] = f2bf(pv[q].x * dm);
            s_vtt[(c + 1) * 136 + m] = f2bf(pv[q].y * dm);
            s_vtt[(c + 2) * 136 + m] = f2bf(pv[q].z * dm);
            s_vtt[(c + 3) * 136 + m] = f2bf(pv[q].w * dm);
        }
    }
    __syncthreads();

    f32x4 acc1[4][2];
#pragma unroll
    for (int ct = 0; ct < 4; ++ct)
#pragma unroll
        for (int mt = 0; mt < 2; ++mt) acc1[ct][mt] = f32x4{0.f, 0.f, 0.f, 0.f};
#pragma unroll
    for (int ks = 0; ks < 4; ++ks)
#pragma unroll
        for (int ct = 0; ct < 4; ++ct) {
            bf16x8 av = *(const bf16x8*)(s_vtt + (ct * 16 + r16) * 136 + ks * 32 + 8 * g);
            acc1[ct][0] = __builtin_amdgcn_mfma_f32_16x16x32_bf16(av, afrag[0][ks], acc1[ct][0], 0, 0, 0);
            acc1[ct][1] = __builtin_amdgcn_mfma_f32_16x16x32_bf16(av, afrag[1][ks], acc1[ct][1], 0, 0, 0);
        }

#pragma unroll
    for (int mt = 0; mt < 2; ++mt) {
        float d = (mt == 0) ? dinv0 : dinv1;
        size_t m = (size_t)(b * 128 + 32 * w + 16 * mt + r16);
#pragma unroll
        for (int ks2 = 0; ks2 < 2; ++ks2) {
            union { unsigned u[4]; bf16x8 v; } pk;
            pk.u[0] = cvt_pk(acc1[2 * ks2][mt][0] * d,     acc1[2 * ks2][mt][1] * d);
            pk.u[1] = cvt_pk(acc1[2 * ks2][mt][2] * d,     acc1[2 * ks2][mt][3] * d);
            pk.u[2] = cvt_pk(acc1[2 * ks2 + 1][mt][0] * d, acc1[2 * ks2 + 1][mt][1] * d);
            pk.u[3] = cvt_pk(acc1[2 * ks2 + 1][mt][2] * d, acc1[2 * ks2 + 1][mt][3] * d);
            *(bf16x8*)(hP + m * 64 + ks2 * 32 + 8 * g) = pk.v;
        }
    }
}

// ---------------- kernel 2: MLP  hP -> out  (v9 = R7 minus prefetch: live <= 128) ----------------
// 512 thr = 8 waves; wave w owns rows (chunk_base + 32w .. +31), FULL width.
// Block: 4 chunks of 256 rows. LDS: W1L 32K | W2L 64K | sh 1.5K (staged once).
// Per T: 4 aw + 8 bw ds_reads feed 24 MFMA. Zero duplicated MFMA (minimal work).
__global__ void __launch_bounds__(512, 2)
gcn_mlp(const unsigned short* __restrict__ hP,
        const unsigned short* __restrict__ W1s, const unsigned short* __restrict__ W2s,
        const float* __restrict__ sh1g, const float* __restrict__ sh2g,
        float* __restrict__ out) {
    __shared__ char smem[99840];
    unsigned short* W1L = (unsigned short*)smem;            // [256][64] u16, swizzled
    unsigned short* W2L = (unsigned short*)(smem + 32768);  // [128][256] u16, swizzled
    float* s_sh1 = (float*)(smem + 98304);
    float* s_sh2 = (float*)(smem + 99328);

    const int t    = threadIdx.x;
    const int lane = t & 63;
    const int w    = t >> 6;
    const int r16  = lane & 15;
    const int g    = lane >> 4;

    // ---- stage weights (linear copy; swizzle baked in by prep) ----
#pragma unroll
    for (int q = 0; q < 4; ++q)
        *(f32x4*)(smem + t * 64 + q * 16) = *(const f32x4*)((const char*)W1s + t * 64 + q * 16);
#pragma unroll
    for (int q = 0; q < 8; ++q)
        *(f32x4*)(smem + 32768 + t * 128 + q * 16) =
            *(const f32x4*)((const char*)W2s + t * 128 + q * 16);
    if (t < 256) s_sh1[t] = sh1g[t];
    if (t < 128) s_sh2[t] = sh2g[t];
    __syncthreads();   // only barrier in the kernel

    const size_t row00 = (size_t)blockIdx.x * 1024;   // 4 chunks x 256 rows

#pragma unroll 1
    for (int i = 0; i < 4; ++i) {
        const size_t mb = row00 + (size_t)i * 256 + 32 * w;   // wave's 32 rows

        // h fragments loaded at chunk start (no cross-chunk prefetch: saves 16 regs)
        bf16x8 bh[2][2];
#pragma unroll
        for (int mt = 0; mt < 2; ++mt)
#pragma unroll
            for (int ks2 = 0; ks2 < 2; ++ks2)
                bh[mt][ks2] = *(const bf16x8*)(hP + (mb + 16 * mt + r16) * 64 + ks2 * 32 + 8 * g);

        f32x4 acc3[2][8];
#pragma unroll
        for (int mt = 0; mt < 2; ++mt)
#pragma unroll
            for (int ct = 0; ct < 8; ++ct) acc3[mt][ct] = f32x4{0.f, 0.f, 0.f, 0.f};

#pragma unroll
        for (int T = 0; T < 8; ++T) {
            // GEMM2: a2[mt][ctp][r] = x1_pre[m=16mt+r16 of wave's 32 rows][c=(2T+ctp)*16+4g+r]
            f32x4 a2[2][2];
#pragma unroll
            for (int mt = 0; mt < 2; ++mt)
#pragma unroll
                for (int ctp = 0; ctp < 2; ++ctp) a2[mt][ctp] = f32x4{0.f, 0.f, 0.f, 0.f};
#pragma unroll
            for (int ctp = 0; ctp < 2; ++ctp) {
                int n = (2 * T + ctp) * 16 + r16;
#pragma unroll
                for (int ks2 = 0; ks2 < 2; ++ks2) {
                    int sp = (ks2 * 4 + g) ^ (n & 7);
                    bf16x8 aw = *(const bf16x8*)(W1L + n * 64 + sp * 8);
                    a2[0][ctp] = __builtin_amdgcn_mfma_f32_16x16x32_bf16(aw, bh[0][ks2], a2[0][ctp], 0, 0, 0);
                    a2[1][ctp] = __builtin_amdgcn_mfma_f32_16x16x32_bf16(aw, bh[1][ks2], a2[1][ctp], 0, 0, 0);
                }
            }
            // BN1 shift + ReLU + bijection pack -> GEMM3 A-frags
            union { unsigned u[4]; bf16x8 v; } af[2];
#pragma unroll
            for (int ctp = 0; ctp < 2; ++ctp) {
                f32x4 sh = *(const f32x4*)(s_sh1 + (2 * T + ctp) * 16 + 4 * g);
#pragma unroll
                for (int mt = 0; mt < 2; ++mt) {
                    float y0 = fmaxf(a2[mt][ctp][0] + sh.x, 0.f);
                    float y1 = fmaxf(a2[mt][ctp][1] + sh.y, 0.f);
                    float y2 = fmaxf(a2[mt][ctp][2] + sh.z, 0.f);
                    float y3 = fmaxf(a2[mt][ctp][3] + sh.w, 0.f);
                    af[mt].u[2 * ctp + 0] = cvt_pk(y0, y1);
                    af[mt].u[2 * ctp + 1] = cvt_pk(y2, y3);
                }
            }
            // GEMM3 partial over k' = 32T..32T+31, full 8 col-tiles (bw reused x2 mt)
#pragma unroll
            for (int ct3 = 0; ct3 < 8; ++ct3) {
                int n  = ct3 * 16 + r16;
                int sp = (T * 4 + g) ^ (n & 7);
                bf16x8 bw = *(const bf16x8*)(W2L + n * 256 + sp * 8);
                acc3[0][ct3] = __builtin_amdgcn_mfma_f32_16x16x32_bf16(af[0].v, bw, acc3[0][ct3], 0, 0, 0);
                acc3[1][ct3] = __builtin_amdgcn_mfma_f32_16x16x32_bf16(af[1].v, bw, acc3[1][ct3], 0, 0, 0);
            }
        }

        // BN2 shift + ReLU -> global
        float* ob = out + mb * 128;
#pragma unroll
        for (int ct3 = 0; ct3 < 8; ++ct3) {
            int c = ct3 * 16 + r16;
            float sh = s_sh2[c];
#pragma unroll
            for (int mt = 0; mt < 2; ++mt)
#pragma unroll
                for (int r = 0; r < 4; ++r) {
                    int row = 16 * mt + 4 * g + r;
                    ob[row * 128 + c] = fmaxf(acc3[mt][ct3][r] + sh, 0.f);
                }
        }
    }
}

extern "C" void kernel_launch(void* const* d_in, const int* in_sizes, int n_in,
                              void* d_out, int out_size, void* d_ws, size_t ws_size,
                              hipStream_t stream) {
    (void)in_sizes; (void)n_in; (void)out_size; (void)ws_size;
    const float* a   = (const float*)d_in[0];
    const float* v   = (const float*)d_in[1];
    const float* W1  = (const float*)d_in[2];
    const float* b1  = (const float*)d_in[3];
    const float* g1  = (const float*)d_in[4];
    const float* be1 = (const float*)d_in[5];
    const float* rm1 = (const float*)d_in[6];
    const float* rv1 = (const float*)d_in[7];
    const float* W2  = (const float*)d_in[8];
    const float* b2  = (const float*)d_in[9];
    const float* g2  = (const float*)d_in[10];
    const float* be2 = (const float*)d_in[11];
    const float* rm2 = (const float*)d_in[12];
    const float* rv2 = (const float*)d_in[13];

    char* ws = (char*)d_ws;
    unsigned short* W1s = (unsigned short*)ws;             // 32768 B
    unsigned short* W2s = (unsigned short*)(ws + 32768);   // 65536 B
    float* sh1 = (float*)(ws + 98304);                     // 1024 B
    float* sh2 = (float*)(ws + 99328);                     // 512 B
    unsigned short* hP = (unsigned short*)(ws + 102400);   // 67108864 B (64 MB)

    gcn_prep<<<128, 256, 0, stream>>>(W1, b1, g1, be1, rm1, rv1,
                                      W2, b2, g2, be2, rm2, rv2,
                                      W1s, W2s, sh1, sh2);
    gcn_prop<<<4096, 256, 0, stream>>>(a, v, hP);
    gcn_mlp<<<512, 512, 0, stream>>>(hP, W1s, W2s, sh1, sh2, (float*)d_out);
}